// Round 11
// baseline (5793.385 us; speedup 1.0000x reference)
//
#include <hip/hip_runtime.h>
#include <hip/hip_bf16.h>
#include <math.h>

#define LB __launch_bounds__(256)

namespace {
constexpr int BB  = 64;     // batch
constexpr int LAT = 512;    // latent
constexpr int FE  = 256;    // n_features
constexpr int TT  = 512;    // seq_len (static per setup_inputs)
constexpr int G4  = 2048;   // 4*latent
constexpr int LO1 = 1024;   // 2T
constexpr int LO2 = 2048;   // 4T
constexpr int NWG = 256;    // persistent grid
constexpr float EPSV = 1e-5f;

// workspace offsets (in floats)
constexpr size_t OFF_WT   = 0;                               // W_comb^T  [2048][512]
constexpr size_t OFF_BC   = OFF_WT  + (size_t)G4 * LAT;      // b_comb    [2048]
constexpr size_t OFF_HT0  = OFF_BC  + G4;                    // h buf0 [512][64] f32
constexpr size_t OFF_HT1  = OFF_HT0 + (size_t)LAT * BB;      // h buf1 [512][64] f32
constexpr size_t OFF_FLG  = OFF_HT1 + (size_t)LAT * BB;      // flags [512] ints
constexpr size_t OFF_W1P  = OFF_FLG + 512;                   // w1 packed [3][256][256]
constexpr size_t OFF_W2P  = OFF_W1P + (size_t)3 * FE * FE;   // w2 packed [3][256][256]
constexpr size_t OFF_A    = OFF_W2P + (size_t)3 * FE * FE;   // A_k       [3][512][256]
constexpr size_t OFF_CBV  = OFF_A   + (size_t)3 * LAT * FE;  // cb_k      [3][256]
constexpr size_t OFF_GSUM = OFF_CBV + 3 * FE;                // [256]
constexpr size_t OFF_GSQ  = OFF_GSUM + FE;                   // [256]
constexpr size_t OFF_BNSC = OFF_GSQ  + FE;                   // [256]
constexpr size_t OFF_BNSH = OFF_BNSC + FE;                   // [256]
constexpr size_t OFF_HS   = OFF_BNSH + FE;                   // H states  [512][64][512]
constexpr size_t OFF_Y1   = OFF_HS  + (size_t)TT * BB * LAT; // deconv1   [64][1024][256]
} // namespace

// ---- device-coherent (sc0 sc1) helpers: R6-proven ordering primitives ----
__device__ __forceinline__ void store_wt_f(float* p, float v) {
    asm volatile("global_store_dword %0, %1, off sc0 sc1" :: "v"(p), "v"(v) : "memory");
}
__device__ __forceinline__ void store_wt_i(int* p, int v) {
    asm volatile("global_store_dword %0, %1, off sc0 sc1" :: "v"(p), "v"(v) : "memory");
}
__device__ __forceinline__ void wait_vm0() {
    asm volatile("s_waitcnt vmcnt(0)" ::: "memory");
    __builtin_amdgcn_sched_barrier(0);
}
__device__ __forceinline__ float sigmoid_fast(float x) {
    return 1.f / (1.f + __expf(-x));
}
__device__ __forceinline__ float tanh_fast(float x) {   // cancellation-free
    float e = __expf(2.f * fminf(x, 15.f));
    return (e - 1.f) / (e + 1.f);
}

// W_comb^T[g][k] = W_hh[g][k] + sum_c W_dense[c][k] * W_ih[g][c]
__global__ LB void k_build_wcomb(const float* __restrict__ Wd, const float* __restrict__ Wih,
                                 const float* __restrict__ Whh, float* __restrict__ Wt) {
    int idx = blockIdx.x * 256 + threadIdx.x;      // 2048*512 total
    int k = idx & (LAT - 1);
    int g = idx >> 9;
    float acc = Whh[(size_t)g * LAT + k];
#pragma unroll 4
    for (int c = 0; c < FE; ++c)
        acc = fmaf(Wd[(size_t)c * LAT + k], Wih[(size_t)g * FE + c], acc);
    Wt[(size_t)g * LAT + k] = acc;
}

// b_comb[g] = b_ih[g] + b_hh[g] + sum_c W_ih[g][c]*b_dense[c]
__global__ LB void k_build_bcomb(const float* __restrict__ Wih, const float* __restrict__ bih,
                                 const float* __restrict__ bhh, const float* __restrict__ bd,
                                 float* __restrict__ bc) {
    int g = blockIdx.x * 256 + threadIdx.x;        // 2048
    float acc = bih[g] + bhh[g];
#pragma unroll 4
    for (int c = 0; c < FE; ++c) acc = fmaf(Wih[(size_t)g * FE + c], bd[c], acc);
    bc[g] = acc;
}

// repack torch [ci][co][k] -> [k][ci][co] for both deconv weights
__global__ LB void k_prepack(const float* __restrict__ w1, const float* __restrict__ w2,
                             float* __restrict__ W1p, float* __restrict__ W2p) {
    int idx = blockIdx.x * 256 + threadIdx.x;      // 6*65536
    int co = idx & 255, ci = (idx >> 8) & 255, r = idx >> 16;
    int tap = r % 3, which = r / 3;
    const float* src = which ? w2 : w1;
    float* dst = which ? W2p : W1p;
    dst[((size_t)tap * FE + ci) * FE + co] = src[((size_t)ci * FE + co) * 3 + tap];
}

// A_k[ki][co] = sum_c W_dense[c][ki] * w1[c][co][k]   (dense fused into deconv1)
__global__ LB void k_build_A(const float* __restrict__ Wd, const float* __restrict__ W1p,
                             float* __restrict__ A) {
    int idx = blockIdx.x * 256 + threadIdx.x;      // 3*512*256
    int co = idx & 255, ki = (idx >> 8) & 511, tap = idx >> 17;
    float acc = 0.f;
#pragma unroll 4
    for (int c = 0; c < FE; ++c)
        acc = fmaf(Wd[(size_t)c * LAT + ki], W1p[((size_t)tap * FE + c) * FE + co], acc);
    A[((size_t)tap * LAT + ki) * FE + co] = acc;
}

// cb_k[co] = sum_c b_dense[c] * w1[c][co][k]
__global__ LB void k_build_cb(const float* __restrict__ bd, const float* __restrict__ W1p,
                              float* __restrict__ cbv) {
    int tap = blockIdx.x, co = threadIdx.x;
    float acc = 0.f;
#pragma unroll 4
    for (int c = 0; c < FE; ++c) acc = fmaf(bd[c], W1p[((size_t)tap * FE + c) * FE + co], acc);
    cbv[tap * FE + co] = acc;
}

// zero flags (replay determinism) + BN accumulators
__global__ LB void k_init_misc(float* __restrict__ gsum, float* __restrict__ gsq,
                               int* __restrict__ flags) {
    int idx = blockIdx.x * 256 + threadIdx.x;      // 512
    if (idx < 512) flags[idx] = 0;
    if (idx < FE) { gsum[idx] = 0.f; gsq[idx] = 0.f; }
}

// issue 16 sc1 f32 loads from base p (stride 256 B) into u[o..o+15]
#define LDP16(o, p)                                                             \
    asm volatile(                                                               \
        "global_load_dword %0,  %16, off sc0 sc1\n\t"                           \
        "global_load_dword %1,  %16, off offset:256 sc0 sc1\n\t"                \
        "global_load_dword %2,  %16, off offset:512 sc0 sc1\n\t"                \
        "global_load_dword %3,  %16, off offset:768 sc0 sc1\n\t"                \
        "global_load_dword %4,  %16, off offset:1024 sc0 sc1\n\t"               \
        "global_load_dword %5,  %16, off offset:1280 sc0 sc1\n\t"               \
        "global_load_dword %6,  %16, off offset:1536 sc0 sc1\n\t"               \
        "global_load_dword %7,  %16, off offset:1792 sc0 sc1\n\t"               \
        "global_load_dword %8,  %16, off offset:2048 sc0 sc1\n\t"               \
        "global_load_dword %9,  %16, off offset:2304 sc0 sc1\n\t"               \
        "global_load_dword %10, %16, off offset:2560 sc0 sc1\n\t"               \
        "global_load_dword %11, %16, off offset:2816 sc0 sc1\n\t"               \
        "global_load_dword %12, %16, off offset:3072 sc0 sc1\n\t"               \
        "global_load_dword %13, %16, off offset:3328 sc0 sc1\n\t"               \
        "global_load_dword %14, %16, off offset:3584 sc0 sc1\n\t"               \
        "global_load_dword %15, %16, off offset:3840 sc0 sc1"                   \
        : "=&v"(u[(o) + 0]), "=&v"(u[(o) + 1]), "=&v"(u[(o) + 2]),              \
          "=&v"(u[(o) + 3]), "=&v"(u[(o) + 4]), "=&v"(u[(o) + 5]),              \
          "=&v"(u[(o) + 6]), "=&v"(u[(o) + 7]), "=&v"(u[(o) + 8]),              \
          "=&v"(u[(o) + 9]), "=&v"(u[(o) + 10]), "=&v"(u[(o) + 11]),            \
          "=&v"(u[(o) + 12]), "=&v"(u[(o) + 13]), "=&v"(u[(o) + 14]),           \
          "=&v"(u[(o) + 15])                                                    \
        : "v"(p))

#define WAITVM(n)                                                               \
    do {                                                                        \
        asm volatile("s_waitcnt vmcnt(" #n ")" ::: "memory");                   \
        __builtin_amdgcn_sched_barrier(0);                                      \
    } while (0)

// FMA 32 k-values (relative B0..B0+31) into acc[8]; one big unfragmented block
#define FMA_HALF(B0)                                                            \
    {                                                                           \
        _Pragma("unroll")                                                       \
        for (int i4 = 0; i4 < 8; ++i4) {                                        \
            const int kk = (B0) + i4 * 4;                                       \
            float h0v = __uint_as_float(u[kk + 0]);                             \
            float h1v = __uint_as_float(u[kk + 1]);                             \
            float h2v = __uint_as_float(u[kk + 2]);                             \
            float h3v = __uint_as_float(u[kk + 3]);                             \
            _Pragma("unroll")                                                   \
            for (int c = 0; c < 8; ++c) {                                       \
                float4 wv = *(const float4*)&w_lds[c][kbase + kk];              \
                acc[c] = fmaf(h3v, wv.w, fmaf(h2v, wv.z,                        \
                         fmaf(h1v, wv.y, fmaf(h0v, wv.x, acc[c]))));            \
            }                                                                   \
        }                                                                       \
    }

// Persistent LSTM scan: R6-proven fp32 write-through payload + ack-then-flag,
// with per-row flags polled directly by every thread (one hop, no aggregate),
// single guaranteed-fresh bulk load, half-split load/FMA overlap.
// 256 WGs x 512 thr; WG w owns latent rows {2w,2w+1} (gate cols s*512+2w+p).
// Thread (b = tid&63, kq = tid>>6): 8 gate cols, K-slice [kq*64, kq*64+64).
__global__ __launch_bounds__(512, 1) void k_lstm_persist9(
    const float* __restrict__ Wt, const float* __restrict__ bc,
    const float* __restrict__ h0, const float* __restrict__ c0,
    float* __restrict__ Ht0, float* __restrict__ Ht1,
    int* __restrict__ flags, float* __restrict__ Hs)
{
    __shared__ float w_lds[8][LAT];      // [c][k], c = s*2+p (16 KB, persistent)
    __shared__ float s_red[8][8][BB];    // [kq][c][b] partials (16 KB)
    const int w = blockIdx.x, tid = threadIdx.x;
    const int b = tid & 63, kq = tid >> 6;

    // stage W slice once: 8 rows x 512 floats = 1024 float4
    for (int i = tid; i < 1024; i += 512) {
        int c = i >> 7, k4 = i & 127;
        int g = (c >> 1) * LAT + 2 * w + (c & 1);
        ((float4*)&w_lds[c][0])[k4] = ((const float4*)&Wt[(size_t)g * LAT])[k4];
    }
    __syncthreads();

    // state-update role: kq<2 threads own latent j = 2w+kq for batch b.
    // Publish h^0 with the R6-proven ordering: data -> wave vmcnt ack -> flag.
    float creg = 0.f, bs0 = 0.f, bs1 = 0.f, bs2 = 0.f, bs3 = 0.f;
    if (kq < 2) {
        int j = 2 * w + kq;
        creg = c0[(size_t)b * LAT + j];
        store_wt_f(&Ht0[j * BB + b], h0[(size_t)b * LAT + j]);
        bs0 = bc[0 * LAT + j];
        bs1 = bc[1 * LAT + j];
        bs2 = bc[2 * LAT + j];
        bs3 = bc[3 * LAT + j];
        wait_vm0();                      // wave's h^0 stores acked at L3
        if (b == 0) store_wt_i(&flags[j], 1);
    }

    const int kbase = kq * 64;
    for (int t = 0; t < TT; ++t) {
        const float* __restrict__ cur = (t & 1) ? Ht1 : Ht0;
        float* __restrict__ nxt = (t & 1) ? Ht0 : Ht1;
        const int ep = t + 1;            // flag value meaning "h^t published"

        // ---- poll per-row flags: thread tid <-> row tid (all 512, no skip —
        // own rows' flags were stored by own waves BEFORE this poll in program
        // order, and run-ahead waves block here until own publish completes,
        // which also protects s_red without a trailing barrier). 2 KB spin.
        {
            const int* fp = flags + tid;
            for (;;) {
                int f;
                asm volatile("global_load_dword %0, %1, off sc0 sc1\n\t"
                             "s_waitcnt vmcnt(0)"
                             : "=&v"(f) : "v"(fp) : "memory");
                if (f >= ep) break;
                __builtin_amdgcn_s_sleep(1);
            }
        }
        __syncthreads();                 // all 512 rows fresh

        // ---- single guaranteed-fresh bulk load (fp32), overlapped halves
        unsigned u[64];
        const float* p = cur + (size_t)kbase * BB + b;
        float acc[8] = {0.f, 0.f, 0.f, 0.f, 0.f, 0.f, 0.f, 0.f};
        LDP16(0, p);
        LDP16(16, p + 16 * BB);
        LDP16(32, p + 32 * BB);
        LDP16(48, p + 48 * BB);
        WAITVM(32);                      // first 32 loads done
        FMA_HALF(0)                      // compute while last 32 in flight
        WAITVM(0);
        FMA_HALF(32)

#pragma unroll
        for (int c = 0; c < 8; ++c) s_red[kq][c][b] = acc[c];
        __syncthreads();

        if (kq < 2) {                    // waves 0-1: gates, update, publish
            int j = 2 * w + kq;
            float gv[4];
#pragma unroll
            for (int s = 0; s < 4; ++s) {
                int c = s * 2 + kq;
                float sum = (s == 0) ? bs0 : (s == 1) ? bs1 : (s == 2) ? bs2 : bs3;
#pragma unroll
                for (int q = 0; q < 8; ++q) sum += s_red[q][c][b];
                gv[s] = sum;
            }
            float ii = sigmoid_fast(gv[0]);
            float ff = sigmoid_fast(gv[1]);
            float tg = tanh_fast(gv[2]);
            float oo = sigmoid_fast(gv[3]);
            creg = ff * creg + ii * tg;
            float hv = oo * tanh_fast(creg);
            store_wt_f(&nxt[j * BB + b], hv);                // h^{t+1} payload
            Hs[((size_t)t * BB + b) * LAT + j] = hv;         // history (cached)
            wait_vm0();                                      // payload acked
            if (b == 0) store_wt_i(&flags[j], t + 2);        // then flag
        }
        // no trailing sync: next step's poll (own rows) + barrier protect s_red
    }
}

// deconv1 (fused dense) + ReLU + BN partial stats.
// grid: 64 b * 32 i-chunks; tile = 16 timesteps x 256 channels, both parities.
__global__ LB void k_deconv1(const float* __restrict__ Hs, const float* __restrict__ A,
                             const float* __restrict__ cbv, const float* __restrict__ b1,
                             float* __restrict__ Y1, float* __restrict__ gsum,
                             float* __restrict__ gsq) {
    __shared__ float x_lds[17][LAT];
    __shared__ float s_sum[FE], s_sq[FE];
    int blk = blockIdx.x;
    int b = blk >> 5, i0 = (blk & 31) << 4;
    int tid = threadIdx.x;
    s_sum[tid] = 0.f; s_sq[tid] = 0.f;
    for (int idx = tid; idx < 17 * LAT; idx += 256) {
        int r = idx >> 9, k = idx & 511;
        int ri = i0 + r;
        x_lds[r][k] = (ri < TT) ? Hs[((size_t)ri * BB + b) * LAT + k] : 0.f;
    }
    __syncthreads();
    int cg0 = tid & 63, rq = tid >> 6;
    int co0 = cg0 << 2;
    float acc[4][4];
    float ps[4] = {0.f, 0.f, 0.f, 0.f}, pq[4] = {0.f, 0.f, 0.f, 0.f};
    // ---- EVEN outputs: tap w1[:,:,1] at i = l/2 ----
#pragma unroll
    for (int q = 0; q < 4; ++q)
#pragma unroll
        for (int cq = 0; cq < 4; ++cq)
            acc[q][cq] = cbv[FE + co0 + cq] + b1[co0 + cq];
    for (int k = 0; k < LAT; ++k) {
        float4 wv = *(const float4*)&A[((size_t)LAT + k) * FE + co0];
#pragma unroll
        for (int q = 0; q < 4; ++q) {
            float xv = x_lds[rq * 4 + q][k];
            acc[q][0] = fmaf(xv, wv.x, acc[q][0]);
            acc[q][1] = fmaf(xv, wv.y, acc[q][1]);
            acc[q][2] = fmaf(xv, wv.z, acc[q][2]);
            acc[q][3] = fmaf(xv, wv.w, acc[q][3]);
        }
    }
#pragma unroll
    for (int q = 0; q < 4; ++q) {
        int l = (i0 + rq * 4 + q) << 1;
        float4 v = { fmaxf(acc[q][0], 0.f), fmaxf(acc[q][1], 0.f),
                     fmaxf(acc[q][2], 0.f), fmaxf(acc[q][3], 0.f) };
        *(float4*)&Y1[((size_t)b * LO1 + l) * FE + co0] = v;
        ps[0] += v.x; pq[0] += v.x * v.x;
        ps[1] += v.y; pq[1] += v.y * v.y;
        ps[2] += v.z; pq[2] += v.z * v.z;
        ps[3] += v.w; pq[3] += v.w * v.w;
    }
    // ---- ODD outputs: w1[:,:,2] at i=(l-1)/2, w1[:,:,0] at i=(l+1)/2 (if valid) ----
#pragma unroll
    for (int q = 0; q < 4; ++q) {
        bool valid0 = (i0 + rq * 4 + q + 1) < TT;
#pragma unroll
        for (int cq = 0; cq < 4; ++cq)
            acc[q][cq] = cbv[2 * FE + co0 + cq] + b1[co0 + cq] +
                         (valid0 ? cbv[co0 + cq] : 0.f);
    }
    for (int k = 0; k < LAT; ++k) {
        float4 w2v = *(const float4*)&A[((size_t)2 * LAT + k) * FE + co0];
        float4 w0v = *(const float4*)&A[(size_t)k * FE + co0];
#pragma unroll
        for (int q = 0; q < 4; ++q) {
            int r = rq * 4 + q;
            float xv2 = x_lds[r][k], xv0 = x_lds[r + 1][k];
            acc[q][0] = fmaf(xv2, w2v.x, fmaf(xv0, w0v.x, acc[q][0]));
            acc[q][1] = fmaf(xv2, w2v.y, fmaf(xv0, w0v.y, acc[q][1]));
            acc[q][2] = fmaf(xv2, w2v.z, fmaf(xv0, w0v.z, acc[q][2]));
            acc[q][3] = fmaf(xv2, w2v.w, fmaf(xv0, w0v.w, acc[q][3]));
        }
    }
#pragma unroll
    for (int q = 0; q < 4; ++q) {
        int l = ((i0 + rq * 4 + q) << 1) + 1;
        float4 v = { fmaxf(acc[q][0], 0.f), fmaxf(acc[q][1], 0.f),
                     fmaxf(acc[q][2], 0.f), fmaxf(acc[q][3], 0.f) };
        *(float4*)&Y1[((size_t)b * LO1 + l) * FE + co0] = v;
        ps[0] += v.x; pq[0] += v.x * v.x;
        ps[1] += v.y; pq[1] += v.y * v.y;
        ps[2] += v.z; pq[2] += v.z * v.z;
        ps[3] += v.w; pq[3] += v.w * v.w;
    }
#pragma unroll
    for (int cq = 0; cq < 4; ++cq) {
        atomicAdd(&s_sum[co0 + cq], ps[cq]);
        atomicAdd(&s_sq[co0 + cq], pq[cq]);
    }
    __syncthreads();
    atomicAdd(&gsum[tid], s_sum[tid]);
    atomicAdd(&gsq[tid], s_sq[tid]);
}

__global__ LB void k_bnfin(const float* __restrict__ gsum, const float* __restrict__ gsq,
                           const float* __restrict__ gamma, const float* __restrict__ beta,
                           float* __restrict__ bnsc, float* __restrict__ bnsh) {
    int co = threadIdx.x;
    float n = (float)(BB * LO1);
    float m = gsum[co] / n;
    float v = gsq[co] / n - m * m;
    float sc = gamma[co] / sqrtf(v + EPSV);
    bnsc[co] = sc;
    bnsh[co] = beta[co] - m * sc;
}

// deconv2: BN applied during LDS staging; writes final output [B][4T][F].
__global__ LB void k_deconv2(const float* __restrict__ Y1, const float* __restrict__ W2p,
                             const float* __restrict__ b2, const float* __restrict__ bnsc,
                             const float* __restrict__ bnsh, float* __restrict__ out) {
    __shared__ float x_lds[17][FE];
    int blk = blockIdx.x;
    int b = blk >> 6, i0 = (blk & 63) << 4;
    int tid = threadIdx.x;
    for (int idx = tid; idx < 17 * FE; idx += 256) {
        int r = idx >> 8, ci = idx & 255;
        int ri = i0 + r;
        x_lds[r][ci] = (ri < LO1)
            ? fmaf(Y1[((size_t)b * LO1 + ri) * FE + ci], bnsc[ci], bnsh[ci]) : 0.f;
    }
    __syncthreads();
    int cg0 = tid & 63, rq = tid >> 6;
    int co0 = cg0 << 2;
    float acc[4][4];
    // ---- EVEN ----
#pragma unroll
    for (int q = 0; q < 4; ++q)
#pragma unroll
        for (int cq = 0; cq < 4; ++cq)
            acc[q][cq] = b2[co0 + cq];
    for (int k = 0; k < FE; ++k) {
        float4 wv = *(const float4*)&W2p[((size_t)FE + k) * FE + co0];
#pragma unroll
        for (int q = 0; q < 4; ++q) {
            float xv = x_lds[rq * 4 + q][k];
            acc[q][0] = fmaf(xv, wv.x, acc[q][0]);
            acc[q][1] = fmaf(xv, wv.y, acc[q][1]);
            acc[q][2] = fmaf(xv, wv.z, acc[q][2]);
            acc[q][3] = fmaf(xv, wv.w, acc[q][3]);
        }
    }
#pragma unroll
    for (int q = 0; q < 4; ++q) {
        int l = (i0 + rq * 4 + q) << 1;
        float4 v = { acc[q][0], acc[q][1], acc[q][2], acc[q][3] };
        *(float4*)&out[((size_t)b * LO2 + l) * FE + co0] = v;
    }
    // ---- ODD ----
#pragma unroll
    for (int q = 0; q < 4; ++q)
#pragma unroll
        for (int cq = 0; cq < 4; ++cq)
            acc[q][cq] = b2[co0 + cq];
    for (int k = 0; k < FE; ++k) {
        float4 w2v = *(const float4*)&W2p[((size_t)2 * FE + k) * FE + co0];
        float4 w0v = *(const float4*)&W2p[(size_t)k * FE + co0];
#pragma unroll
        for (int q = 0; q < 4; ++q) {
            int r = rq * 4 + q;
            float xv2 = x_lds[r][k], xv0 = x_lds[r + 1][k];
            acc[q][0] = fmaf(xv2, w2v.x, fmaf(xv0, w0v.x, acc[q][0]));
            acc[q][1] = fmaf(xv2, w2v.y, fmaf(xv0, w0v.y, acc[q][1]));
            acc[q][2] = fmaf(xv2, w2v.z, fmaf(xv0, w0v.z, acc[q][2]));
            acc[q][3] = fmaf(xv2, w2v.w, fmaf(xv0, w0v.w, acc[q][3]));
        }
    }
#pragma unroll
    for (int q = 0; q < 4; ++q) {
        int l = ((i0 + rq * 4 + q) << 1) + 1;
        float4 v = { acc[q][0], acc[q][1], acc[q][2], acc[q][3] };
        *(float4*)&out[((size_t)b * LO2 + l) * FE + co0] = v;
    }
}

extern "C" void kernel_launch(void* const* d_in, const int* in_sizes, int n_in,
                              void* d_out, int out_size, void* d_ws, size_t ws_size,
                              hipStream_t stream) {
    const float* h0    = (const float*)d_in[0];
    const float* c0    = (const float*)d_in[1];
    // d_in[2] = seq_len (int, statically 512)
    const float* Wih   = (const float*)d_in[3];
    const float* bih   = (const float*)d_in[4];
    const float* Whh   = (const float*)d_in[5];
    const float* bhh   = (const float*)d_in[6];
    const float* Wd    = (const float*)d_in[7];
    const float* bd    = (const float*)d_in[8];
    const float* w1    = (const float*)d_in[9];
    const float* b1    = (const float*)d_in[10];
    const float* w2    = (const float*)d_in[11];
    const float* b2    = (const float*)d_in[12];
    const float* gamma = (const float*)d_in[13];
    const float* beta  = (const float*)d_in[14];

    float* ws   = (float*)d_ws;
    float* Wt   = ws + OFF_WT;
    float* bc   = ws + OFF_BC;
    float* Ht0  = ws + OFF_HT0;
    float* Ht1  = ws + OFF_HT1;
    int*   flg  = (int*)(ws + OFF_FLG);
    float* W1p  = ws + OFF_W1P;
    float* W2p  = ws + OFF_W2P;
    float* A    = ws + OFF_A;
    float* cbv  = ws + OFF_CBV;
    float* gsum = ws + OFF_GSUM;
    float* gsq  = ws + OFF_GSQ;
    float* bnsc = ws + OFF_BNSC;
    float* bnsh = ws + OFF_BNSH;
    float* Hs   = ws + OFF_HS;
    float* Y1   = ws + OFF_Y1;
    float* out  = (float*)d_out;

    k_build_wcomb<<<4096, 256, 0, stream>>>(Wd, Wih, Whh, Wt);
    k_build_bcomb<<<8, 256, 0, stream>>>(Wih, bih, bhh, bd, bc);
    k_prepack<<<1536, 256, 0, stream>>>(w1, w2, W1p, W2p);
    k_build_A<<<1536, 256, 0, stream>>>(Wd, W1p, A);
    k_build_cb<<<3, 256, 0, stream>>>(bd, W1p, cbv);
    k_init_misc<<<2, 256, 0, stream>>>(gsum, gsq, flg);

    {
        const float* a0 = Wt;  const float* a1 = bc;
        const float* a2 = h0;  const float* a3 = c0;
        float* a4 = Ht0; float* a5 = Ht1;
        int* a6 = flg; float* a7 = Hs;
        void* args[] = { (void*)&a0, (void*)&a1, (void*)&a2, (void*)&a3,
                         (void*)&a4, (void*)&a5, (void*)&a6, (void*)&a7 };
        hipLaunchCooperativeKernel((const void*)k_lstm_persist9, dim3(NWG), dim3(512),
                                   args, 0, stream);
    }

    k_deconv1<<<2048, 256, 0, stream>>>(Hs, A, cbv, b1, Y1, gsum, gsq);
    k_bnfin<<<1, 256, 0, stream>>>(gsum, gsq, gamma, beta, bnsc, bnsh);
    k_deconv2<<<4096, 256, 0, stream>>>(Y1, W2p, b2, bnsc, bnsh, out);
}

// Round 12
// 3488.298 us; speedup vs baseline: 1.6608x; 1.6608x over previous
//
#include <hip/hip_runtime.h>
#include <hip/hip_bf16.h>
#include <math.h>

#define LB __launch_bounds__(256)

namespace {
constexpr int BB  = 64;     // batch
constexpr int LAT = 512;    // latent
constexpr int FE  = 256;    // n_features
constexpr int TT  = 512;    // seq_len
constexpr int G4  = 2048;   // 4*latent
constexpr int LO1 = 1024;   // 2T
constexpr int LO2 = 2048;   // 4T
constexpr int NWG = 256;    // persistent grid
constexpr int Y1S = 1025;   // Y1 row stride per batch (l=0..1023 + zero pad row)
constexpr float EPSV = 1e-5f;

// workspace offsets (floats)
constexpr size_t OFF_WT   = 0;                                // W_comb^T [2048][512] f32
constexpr size_t OFF_BC   = OFF_WT  + (size_t)G4 * LAT;       // b_comb [2048]
constexpr size_t OFF_HX0  = OFF_BC  + G4;                     // tagged pairs buf0 [512][64] u32
constexpr size_t OFF_HX1  = OFF_HX0 + (size_t)LAT * BB;
constexpr size_t OFF_A    = OFF_HX1 + (size_t)LAT * BB;       // A [3][512][256] f32
constexpr size_t OFF_CBV  = OFF_A   + (size_t)3 * LAT * FE;   // cbv [3][256]
constexpr size_t OFF_GSUM = OFF_CBV + 3 * FE;
constexpr size_t OFF_GSQ  = OFF_GSUM + FE;
constexpr size_t OFF_BNSC = OFF_GSQ  + FE;
constexpr size_t OFF_BNSH = OFF_BNSC + FE;
constexpr size_t OFF_BSH  = OFF_BNSH + FE;                    // bias_sh [3][256]
constexpr size_t OFF_BP1  = OFF_BSH + 3 * FE;                 // Bpack1: 3*16*16*64*8 bf16
constexpr size_t OFF_BP2  = OFF_BP1 + (size_t)3*16*16*64*8/2; // Bpack2: 3*8*16*64*8 bf16
constexpr size_t OFF_HSB  = OFF_BP2 + (size_t)3*8*16*64*8/2;  // Hs bf16 [513*64][512]
constexpr size_t OFF_Y1P  = OFF_HSB + (size_t)513*64*512/2;   // Y1 bf16 [64][1025][256]
} // namespace

typedef __attribute__((ext_vector_type(8))) short s8v;
typedef __attribute__((ext_vector_type(4))) float f4v;

// ---- device-coherent (sc0 sc1) helpers ----
__device__ __forceinline__ void store_wt_u(unsigned* p, unsigned v) {
    asm volatile("global_store_dword %0, %1, off sc0 sc1" :: "v"(p), "v"(v) : "memory");
}
// pack h (RN bf16 hi16) + epoch tag (lo16) in ONE dword: atomic data+validity
__device__ __forceinline__ unsigned pack_pair(float h, int ep) {
    return ((__float_as_uint(h) + 0x8000u) & 0xFFFF0000u) | (unsigned)ep;
}
__device__ __forceinline__ unsigned short f2bf(float h) {
    return (unsigned short)((__float_as_uint(h) + 0x8000u) >> 16);
}
__device__ __forceinline__ float sigmoid_fast(float x) {
    return 1.f / (1.f + __expf(-x));
}
__device__ __forceinline__ float tanh_fast(float x) {   // cancellation-free
    float e = __expf(2.f * fminf(x, 15.f));
    return (e - 1.f) / (e + 1.f);
}

// W_comb^T[g][k] = W_hh[g][k] + sum_c W_dense[c][k] * W_ih[g][c]
__global__ LB void k_build_wcomb(const float* __restrict__ Wd, const float* __restrict__ Wih,
                                 const float* __restrict__ Whh, float* __restrict__ Wt) {
    int idx = blockIdx.x * 256 + threadIdx.x;
    int k = idx & (LAT - 1);
    int g = idx >> 9;
    float acc = Whh[(size_t)g * LAT + k];
#pragma unroll 4
    for (int c = 0; c < FE; ++c)
        acc = fmaf(Wd[(size_t)c * LAT + k], Wih[(size_t)g * FE + c], acc);
    Wt[(size_t)g * LAT + k] = acc;
}

// b_comb[g] = b_ih[g] + b_hh[g] + sum_c W_ih[g][c]*b_dense[c]
__global__ LB void k_build_bcomb(const float* __restrict__ Wih, const float* __restrict__ bih,
                                 const float* __restrict__ bhh, const float* __restrict__ bd,
                                 float* __restrict__ bc) {
    int g = blockIdx.x * 256 + threadIdx.x;
    float acc = bih[g] + bhh[g];
#pragma unroll 4
    for (int c = 0; c < FE; ++c) acc = fmaf(Wih[(size_t)g * FE + c], bd[c], acc);
    bc[g] = acc;
}

// A[tap][k][co] = sum_c Wd[c][k] * w1[c][co][tap]   (dense fused into deconv1)
__global__ LB void k_build_A(const float* __restrict__ Wd, const float* __restrict__ w1,
                             float* __restrict__ A) {
    int idx = blockIdx.x * 256 + threadIdx.x;      // 3*512*256
    int co = idx & 255, ki = (idx >> 8) & 511, tap = idx >> 17;
    float acc = 0.f;
#pragma unroll 4
    for (int c = 0; c < FE; ++c)
        acc = fmaf(Wd[(size_t)c * LAT + ki], w1[((size_t)c * FE + co) * 3 + tap], acc);
    A[((size_t)tap * LAT + ki) * FE + co] = acc;
}

// cbv[tap][co] = sum_c bd[c] * w1[c][co][tap]
__global__ LB void k_build_cb(const float* __restrict__ bd, const float* __restrict__ w1,
                              float* __restrict__ cbv) {
    int tap = blockIdx.x, co = threadIdx.x;
    float acc = 0.f;
#pragma unroll 4
    for (int c = 0; c < FE; ++c) acc = fmaf(bd[c], w1[((size_t)c * FE + co) * 3 + tap], acc);
    cbv[tap * FE + co] = acc;
}

// Bpack1: fragment-major bf16 layout of A for 16x16x32 MFMA B-operand.
// dst[tap][ks(16)][ct(16)][lane(64)][j(8)] = A[tap][ks*32+(lane>>4)*8+j][ct*16+(lane&15)]
__global__ LB void k_bpack1(const float* __restrict__ A, unsigned short* __restrict__ Bp1) {
    int idx = blockIdx.x * 256 + threadIdx.x;      // 393216
    int j = idx & 7, lane = (idx >> 3) & 63, ct = (idx >> 9) & 15;
    int ks = (idx >> 13) & 15, tap = idx >> 17;
    int k = ks * 32 + (lane >> 4) * 8 + j;
    int co = ct * 16 + (lane & 15);
    Bp1[idx] = f2bf(A[((size_t)tap * LAT + k) * FE + co]);
}

// zero tag buffers + BN accumulators (replay determinism)
__global__ LB void k_init_misc(float* __restrict__ gsum, float* __restrict__ gsq,
                               unsigned* __restrict__ Hx0, unsigned* __restrict__ Hx1) {
    int idx = blockIdx.x * 256 + threadIdx.x;      // 32768
    Hx0[idx] = 0u;
    Hx1[idx] = 0u;
    if (idx < FE) { gsum[idx] = 0.f; gsq[idx] = 0.f; }
}

// zero pad rows: Hs_bf t=512 (64x512) and Y1p row 1024 per batch (64x256)
__global__ LB void k_init_pads(unsigned short* __restrict__ Hsb,
                               unsigned short* __restrict__ Y1p) {
    int idx = blockIdx.x * 256 + threadIdx.x;      // 49152
    if (idx < 32768) {
        Hsb[(size_t)512 * BB * LAT + idx] = 0;
    } else {
        int j = idx - 32768;
        int b = j >> 8, co = j & 255;
        Y1p[((size_t)b * Y1S + 1024) * FE + co] = 0;
    }
}

// issue 16 sc1 pair loads from base p (stride 256 B) into u[o..o+15]
#define LDP16(o, p)                                                             \
    asm volatile(                                                               \
        "global_load_dword %0,  %16, off sc0 sc1\n\t"                           \
        "global_load_dword %1,  %16, off offset:256 sc0 sc1\n\t"                \
        "global_load_dword %2,  %16, off offset:512 sc0 sc1\n\t"                \
        "global_load_dword %3,  %16, off offset:768 sc0 sc1\n\t"                \
        "global_load_dword %4,  %16, off offset:1024 sc0 sc1\n\t"               \
        "global_load_dword %5,  %16, off offset:1280 sc0 sc1\n\t"               \
        "global_load_dword %6,  %16, off offset:1536 sc0 sc1\n\t"               \
        "global_load_dword %7,  %16, off offset:1792 sc0 sc1\n\t"               \
        "global_load_dword %8,  %16, off offset:2048 sc0 sc1\n\t"               \
        "global_load_dword %9,  %16, off offset:2304 sc0 sc1\n\t"               \
        "global_load_dword %10, %16, off offset:2560 sc0 sc1\n\t"               \
        "global_load_dword %11, %16, off offset:2816 sc0 sc1\n\t"               \
        "global_load_dword %12, %16, off offset:3072 sc0 sc1\n\t"               \
        "global_load_dword %13, %16, off offset:3328 sc0 sc1\n\t"               \
        "global_load_dword %14, %16, off offset:3584 sc0 sc1\n\t"               \
        "global_load_dword %15, %16, off offset:3840 sc0 sc1"                   \
        : "=&v"(u[(o) + 0]), "=&v"(u[(o) + 1]), "=&v"(u[(o) + 2]),              \
          "=&v"(u[(o) + 3]), "=&v"(u[(o) + 4]), "=&v"(u[(o) + 5]),              \
          "=&v"(u[(o) + 6]), "=&v"(u[(o) + 7]), "=&v"(u[(o) + 8]),              \
          "=&v"(u[(o) + 9]), "=&v"(u[(o) + 10]), "=&v"(u[(o) + 11]),            \
          "=&v"(u[(o) + 12]), "=&v"(u[(o) + 13]), "=&v"(u[(o) + 14]),           \
          "=&v"(u[(o) + 15])                                                    \
        : "v"(p))

// Persistent LSTM scan: R7 tagged-dataflow + s_red dbuf + run-ahead (no trailing
// sync). 256 WGs x 512 thr; WG w owns latent rows {2w,2w+1}.
// Thread (b = tid&63, kq = tid>>6): 8 gate cols, K-slice [kq*64, kq*64+64).
__global__ __launch_bounds__(512, 1) void k_lstm_persist10(
    const float* __restrict__ Wt, const float* __restrict__ bc,
    const float* __restrict__ h0, const float* __restrict__ c0,
    unsigned* __restrict__ Hx0, unsigned* __restrict__ Hx1,
    unsigned short* __restrict__ Hsb)
{
    __shared__ float w_lds[8][LAT];        // 16 KB persistent
    __shared__ float s_red[2][8][8][BB];   // dbuf partials (32 KB)
    const int w = blockIdx.x, tid = threadIdx.x;
    const int b = tid & 63, kq = tid >> 6;

    for (int i = tid; i < 1024; i += 512) {
        int c = i >> 7, k4 = i & 127;
        int g = (c >> 1) * LAT + 2 * w + (c & 1);
        ((float4*)&w_lds[c][0])[k4] = ((const float4*)&Wt[(size_t)g * LAT])[k4];
    }
    __syncthreads();

    float creg = 0.f, bs0 = 0.f, bs1 = 0.f, bs2 = 0.f, bs3 = 0.f;
    if (kq < 2) {
        int j = 2 * w + kq;
        creg = c0[(size_t)b * LAT + j];
        store_wt_u(&Hx0[j * BB + b], pack_pair(h0[(size_t)b * LAT + j], 1));
        bs0 = bc[0 * LAT + j];
        bs1 = bc[1 * LAT + j];
        bs2 = bc[2 * LAT + j];
        bs3 = bc[3 * LAT + j];
    }

    const int kbase = kq * 64;
    for (int t = 0; t < TT; ++t) {
        const unsigned* __restrict__ cur = (t & 1) ? Hx1 : Hx0;
        unsigned* __restrict__ nxt = (t & 1) ? Hx0 : Hx1;
        const int ep = t + 1;

        // monolithic optimistic load + validate (R7-proven; compiler-friendly)
        unsigned u[64];
        const unsigned* pbase = cur + (size_t)kbase * BB + b;
        int mn;
        for (;;) {
            LDP16(0, pbase);
            LDP16(16, pbase + 16 * BB);
            LDP16(32, pbase + 32 * BB);
            LDP16(48, pbase + 48 * BB);
            asm volatile("s_waitcnt vmcnt(0)" ::: "memory");
            __builtin_amdgcn_sched_barrier(0);
            mn = 0x7fffffff;
#pragma unroll
            for (int i = 0; i < 64; ++i) mn = min(mn, (int)(u[i] & 0xFFFFu));
            if (mn >= ep) break;
            __builtin_amdgcn_s_sleep(2);
        }

        float acc[8] = {0.f, 0.f, 0.f, 0.f, 0.f, 0.f, 0.f, 0.f};
#pragma unroll
        for (int i4 = 0; i4 < 16; ++i4) {
            int k = kbase + i4 * 4;
            float h0v = __uint_as_float(u[i4 * 4 + 0]);
            float h1v = __uint_as_float(u[i4 * 4 + 1]);
            float h2v = __uint_as_float(u[i4 * 4 + 2]);
            float h3v = __uint_as_float(u[i4 * 4 + 3]);
#pragma unroll
            for (int c = 0; c < 8; ++c) {
                float4 wv = *(const float4*)&w_lds[c][k];
                acc[c] = fmaf(h3v, wv.w, fmaf(h2v, wv.z,
                         fmaf(h1v, wv.y, fmaf(h0v, wv.x, acc[c]))));
            }
        }
        float (*sr)[8][BB] = s_red[t & 1];
#pragma unroll
        for (int c = 0; c < 8; ++c) sr[kq][c][b] = acc[c];
        __syncthreads();

        if (kq < 2) {                    // waves 0-1: gates, update, publish
            int j = 2 * w + kq;
            float gv[4];
#pragma unroll
            for (int s = 0; s < 4; ++s) {
                int c = s * 2 + kq;
                float sum = (s == 0) ? bs0 : (s == 1) ? bs1 : (s == 2) ? bs2 : bs3;
#pragma unroll
                for (int q = 0; q < 8; ++q) sum += sr[q][c][b];
                gv[s] = sum;
            }
            float ii = sigmoid_fast(gv[0]);
            float ff = sigmoid_fast(gv[1]);
            float tg = tanh_fast(gv[2]);
            float oo = sigmoid_fast(gv[3]);
            creg = ff * creg + ii * tg;
            float hv = oo * tanh_fast(creg);
            unsigned pk = pack_pair(hv, t + 2);
            store_wt_u(&nxt[j * BB + b], pk);                     // publish h^{t+1}
            Hsb[((size_t)t * BB + b) * LAT + j] = (unsigned short)(pk >> 16);
        }
        // no trailing sync: s_red double-buffered; other waves run ahead
    }
}

// MFMA deconv1: even/odd outputs as 3 GEMMs (taps 1,2,0; tap0 uses rows+64,
// boundary handled by zero pad rows + bias correction). relu + BN stats + bf16 Y1.
__global__ LB void k_mfma_dc1(const unsigned short* __restrict__ Hsb,
                              const unsigned short* __restrict__ Bp1,
                              const float* __restrict__ cbv, const float* __restrict__ b1,
                              unsigned short* __restrict__ Y1p,
                              float* __restrict__ gsum, float* __restrict__ gsq) {
    __shared__ float s_sum[64], s_sq[64];
    int blk = blockIdx.x;                // 2048: bm(512) x bn(4)
    int bm = blk >> 2, bn = blk & 3;
    int tid = threadIdx.x, wv = tid >> 6, lane = tid & 63;
    if (tid < 64) { s_sum[tid] = 0.f; s_sq[tid] = 0.f; }
    __syncthreads();
    int m0 = bm * 64 + wv * 16;
    const unsigned short* pa = Hsb + (size_t)(m0 + (lane & 15)) * LAT + (lane >> 4) * 8;
    const unsigned short* pas = pa + (size_t)64 * LAT;   // rows r+64 (i+1)
    f4v acce[4] = {0.f,0.f,0.f,0.f}, acco[4];
#pragma unroll
    for (int c = 0; c < 4; ++c) { acce[c] = (f4v){0.f,0.f,0.f,0.f}; acco[c] = (f4v){0.f,0.f,0.f,0.f}; }
    for (int ks = 0; ks < 16; ++ks) {
        s8v av = *(const s8v*)(pa + ks * 32);
        s8v as = *(const s8v*)(pas + ks * 32);
#pragma unroll
        for (int c = 0; c < 4; ++c) {
            int ct = bn * 4 + c;
            const size_t fb = ((size_t)ks * 16 + ct) * 64 + lane;
            s8v bf1 = *(const s8v*)(Bp1 + (((size_t)1 * 16 * 16 * 64) + fb) * 8);
            s8v bf2 = *(const s8v*)(Bp1 + (((size_t)2 * 16 * 16 * 64) + fb) * 8);
            s8v bf0 = *(const s8v*)(Bp1 + (fb) * 8);
            acce[c] = __builtin_amdgcn_mfma_f32_16x16x32_bf16(av, bf1, acce[c], 0, 0, 0);
            acco[c] = __builtin_amdgcn_mfma_f32_16x16x32_bf16(av, bf2, acco[c], 0, 0, 0);
            acco[c] = __builtin_amdgcn_mfma_f32_16x16x32_bf16(as, bf0, acco[c], 0, 0, 0);
        }
    }
#pragma unroll
    for (int c = 0; c < 4; ++c) {
        int col = bn * 64 + c * 16 + (lane & 15);
        float be = cbv[FE + col] + b1[col];
        float bo = cbv[2 * FE + col] + b1[col] + cbv[col];
        float c0v = cbv[col];
        float ps = 0.f, pq = 0.f;
#pragma unroll
        for (int q = 0; q < 4; ++q) {
            int r = m0 + (lane >> 4) * 4 + q;      // C/D: row=(lane>>4)*4+q, col=lane&15
            int i = r >> 6, b = r & 63;
            float ve = acce[c][q] + be;
            float vo = acco[c][q] + bo;
            if (i == TT - 1) vo -= c0v;            // tap0 invalid at i+1==512
            ve = fmaxf(ve, 0.f);
            vo = fmaxf(vo, 0.f);
            size_t base = ((size_t)b * Y1S + 2 * i) * FE + col;
            Y1p[base] = f2bf(ve);
            Y1p[base + FE] = f2bf(vo);
            ps += ve + vo;
            pq += ve * ve + vo * vo;
        }
        atomicAdd(&s_sum[c * 16 + (lane & 15)], ps);
        atomicAdd(&s_sq[c * 16 + (lane & 15)], pq);
    }
    __syncthreads();
    if (tid < 64) {
        atomicAdd(&gsum[bn * 64 + tid], s_sum[tid]);
        atomicAdd(&gsq[bn * 64 + tid], s_sq[tid]);
    }
}

__global__ LB void k_bnfin(const float* __restrict__ gsum, const float* __restrict__ gsq,
                           const float* __restrict__ gamma, const float* __restrict__ beta,
                           float* __restrict__ bnsc, float* __restrict__ bnsh) {
    int co = threadIdx.x;
    float n = (float)(BB * LO1);
    float m = gsum[co] / n;
    float v = gsq[co] / n - m * m;
    float sc = gamma[co] / sqrtf(v + EPSV);
    bnsc[co] = sc;
    bnsh[co] = beta[co] - m * sc;
}

// bias_sh[tap][co] = sum_ci bnsh[ci] * w2[ci][co][tap]
__global__ LB void k_fold_bias2(const float* __restrict__ bnsh, const float* __restrict__ w2,
                                float* __restrict__ bsh) {
    int tap = blockIdx.x, co = threadIdx.x;
    float acc = 0.f;
#pragma unroll 4
    for (int c = 0; c < FE; ++c) acc = fmaf(bnsh[c], w2[((size_t)c * FE + co) * 3 + tap], acc);
    bsh[tap * FE + co] = acc;
}

// Bpack2: fragment-major bf16 of (bnsc-folded) w2: [tap][ks(8)][ct(16)][lane][8]
__global__ LB void k_bpack2(const float* __restrict__ bnsc, const float* __restrict__ w2,
                            unsigned short* __restrict__ Bp2) {
    int idx = blockIdx.x * 256 + threadIdx.x;      // 196608
    int j = idx & 7, lane = (idx >> 3) & 63, ct = (idx >> 9) & 15;
    int ks = (idx >> 13) & 7, tap = idx >> 16;
    int ci = ks * 32 + (lane >> 4) * 8 + j;
    int co = ct * 16 + (lane & 15);
    Bp2[idx] = f2bf(bnsc[ci] * w2[((size_t)ci * FE + co) * 3 + tap]);
}

// MFMA deconv2: BN folded into weights; reads bf16 Y1 (pad row 1024 = 0),
// writes fp32 output [B][4T][F].
__global__ LB void k_mfma_dc2(const unsigned short* __restrict__ Y1p,
                              const unsigned short* __restrict__ Bp2,
                              const float* __restrict__ b2, const float* __restrict__ bsh,
                              float* __restrict__ out) {
    int blk = blockIdx.x;                // 4096: b(64) x lt(16) x bn(4)
    int b = blk >> 6, lt = (blk >> 2) & 15, bn = blk & 3;
    int tid = threadIdx.x, wv = tid >> 6, lane = tid & 63;
    int l0 = lt * 64 + wv * 16;
    const unsigned short* pa = Y1p + ((size_t)b * Y1S + l0 + (lane & 15)) * FE + (lane >> 4) * 8;
    const unsigned short* pas = pa + FE;           // rows l+1 (pad at 1024)
    f4v acce[4], acco[4];
#pragma unroll
    for (int c = 0; c < 4; ++c) { acce[c] = (f4v){0.f,0.f,0.f,0.f}; acco[c] = (f4v){0.f,0.f,0.f,0.f}; }
    for (int ks = 0; ks < 8; ++ks) {
        s8v av = *(const s8v*)(pa + ks * 32);
        s8v as = *(const s8v*)(pas + ks * 32);
#pragma unroll
        for (int c = 0; c < 4; ++c) {
            int ct = bn * 4 + c;
            const size_t fb = ((size_t)ks * 16 + ct) * 64 + lane;
            s8v bf1 = *(const s8v*)(Bp2 + (((size_t)1 * 8 * 16 * 64) + fb) * 8);
            s8v bf2 = *(const s8v*)(Bp2 + (((size_t)2 * 8 * 16 * 64) + fb) * 8);
            s8v bf0 = *(const s8v*)(Bp2 + (fb) * 8);
            acce[c] = __builtin_amdgcn_mfma_f32_16x16x32_bf16(av, bf1, acce[c], 0, 0, 0);
            acco[c] = __builtin_amdgcn_mfma_f32_16x16x32_bf16(av, bf2, acco[c], 0, 0, 0);
            acco[c] = __builtin_amdgcn_mfma_f32_16x16x32_bf16(as, bf0, acco[c], 0, 0, 0);
        }
    }
#pragma unroll
    for (int c = 0; c < 4; ++c) {
        int col = bn * 64 + c * 16 + (lane & 15);
        float be = b2[col] + bsh[FE + col];
        float bo = b2[col] + bsh[2 * FE + col] + bsh[col];
        float s0 = bsh[col];
#pragma unroll
        for (int q = 0; q < 4; ++q) {
            int l = l0 + (lane >> 4) * 4 + q;
            float ve = acce[c][q] + be;
            float vo = acco[c][q] + bo;
            if (l == LO1 - 1) vo -= s0;            // tap0 invalid at l+1==1024
            size_t base = ((size_t)b * LO2 + 2 * l) * FE + col;
            out[base] = ve;
            out[base + FE] = vo;
        }
    }
}

extern "C" void kernel_launch(void* const* d_in, const int* in_sizes, int n_in,
                              void* d_out, int out_size, void* d_ws, size_t ws_size,
                              hipStream_t stream) {
    const float* h0    = (const float*)d_in[0];
    const float* c0    = (const float*)d_in[1];
    // d_in[2] = seq_len (int, statically 512)
    const float* Wih   = (const float*)d_in[3];
    const float* bih   = (const float*)d_in[4];
    const float* Whh   = (const float*)d_in[5];
    const float* bhh   = (const float*)d_in[6];
    const float* Wd    = (const float*)d_in[7];
    const float* bd    = (const float*)d_in[8];
    const float* w1    = (const float*)d_in[9];
    const float* b1    = (const float*)d_in[10];
    const float* w2    = (const float*)d_in[11];
    const float* b2    = (const float*)d_in[12];
    const float* gamma = (const float*)d_in[13];
    const float* beta  = (const float*)d_in[14];

    float* ws   = (float*)d_ws;
    float* Wt   = ws + OFF_WT;
    float* bc   = ws + OFF_BC;
    unsigned* Hx0 = (unsigned*)(ws + OFF_HX0);
    unsigned* Hx1 = (unsigned*)(ws + OFF_HX1);
    float* A    = ws + OFF_A;
    float* cbv  = ws + OFF_CBV;
    float* gsum = ws + OFF_GSUM;
    float* gsq  = ws + OFF_GSQ;
    float* bnsc = ws + OFF_BNSC;
    float* bnsh = ws + OFF_BNSH;
    float* bsh  = ws + OFF_BSH;
    unsigned short* Bp1 = (unsigned short*)(ws + OFF_BP1);
    unsigned short* Bp2 = (unsigned short*)(ws + OFF_BP2);
    unsigned short* Hsb = (unsigned short*)(ws + OFF_HSB);
    unsigned short* Y1p = (unsigned short*)(ws + OFF_Y1P);
    float* out  = (float*)d_out;

    k_build_wcomb<<<4096, 256, 0, stream>>>(Wd, Wih, Whh, Wt);
    k_build_bcomb<<<8, 256, 0, stream>>>(Wih, bih, bhh, bd, bc);
    k_build_A<<<1536, 256, 0, stream>>>(Wd, w1, A);
    k_build_cb<<<3, 256, 0, stream>>>(bd, w1, cbv);
    k_bpack1<<<1536, 256, 0, stream>>>(A, Bp1);
    k_init_misc<<<128, 256, 0, stream>>>(gsum, gsq, Hx0, Hx1);
    k_init_pads<<<192, 256, 0, stream>>>(Hsb, Y1p);

    {
        const float* a0 = Wt;  const float* a1 = bc;
        const float* a2 = h0;  const float* a3 = c0;
        unsigned* a4 = Hx0; unsigned* a5 = Hx1; unsigned short* a6 = Hsb;
        void* args[] = { (void*)&a0, (void*)&a1, (void*)&a2, (void*)&a3,
                         (void*)&a4, (void*)&a5, (void*)&a6 };
        hipLaunchCooperativeKernel((const void*)k_lstm_persist10, dim3(NWG), dim3(512),
                                   args, 0, stream);
    }

    k_mfma_dc1<<<2048, 256, 0, stream>>>(Hsb, Bp1, cbv, b1, Y1p, gsum, gsq);
    k_bnfin<<<1, 256, 0, stream>>>(gsum, gsq, gamma, beta, bnsc, bnsh);
    k_fold_bias2<<<3, 256, 0, stream>>>(bnsh, w2, bsh);
    k_bpack2<<<768, 256, 0, stream>>>(bnsc, w2, Bp2);
    k_mfma_dc2<<<4096, 256, 0, stream>>>(Y1p, Bp2, b2, bsh, out);
}

// Round 13
// 3108.221 us; speedup vs baseline: 1.8639x; 1.1223x over previous
//
#include <hip/hip_runtime.h>
#include <hip/hip_bf16.h>
#include <math.h>

#define LB __launch_bounds__(256)

namespace {
constexpr int BB  = 64;     // batch
constexpr int LAT = 512;    // latent
constexpr int FE  = 256;    // n_features
constexpr int TT  = 512;    // seq_len
constexpr int G4  = 2048;   // 4*latent
constexpr int LO1 = 1024;   // 2T
constexpr int LO2 = 2048;   // 4T
constexpr int NWG = 256;    // persistent grid
constexpr int Y1S = 1025;   // Y1 row stride per batch (l=0..1023 + zero pad row)
constexpr float EPSV = 1e-5f;

// workspace offsets (floats)
constexpr size_t OFF_WT   = 0;                                // W_comb^T [2048][512] f32
constexpr size_t OFF_BC   = OFF_WT  + (size_t)G4 * LAT;       // b_comb [2048]
constexpr size_t OFF_HX0  = OFF_BC  + G4;                     // tagged pairs buf0 [512][64] u32
constexpr size_t OFF_HX1  = OFF_HX0 + (size_t)LAT * BB;
constexpr size_t OFF_A    = OFF_HX1 + (size_t)LAT * BB;       // A [3][512][256] f32
constexpr size_t OFF_CBV  = OFF_A   + (size_t)3 * LAT * FE;   // cbv [3][256]
constexpr size_t OFF_GSUM = OFF_CBV + 3 * FE;
constexpr size_t OFF_GSQ  = OFF_GSUM + FE;
constexpr size_t OFF_BNSC = OFF_GSQ  + FE;
constexpr size_t OFF_BNSH = OFF_BNSC + FE;
constexpr size_t OFF_BSH  = OFF_BNSH + FE;                    // bias_sh [3][256]
constexpr size_t OFF_BP1  = OFF_BSH + 3 * FE;                 // Bpack1: 3*16*16*64*8 bf16
constexpr size_t OFF_BP2  = OFF_BP1 + (size_t)3*16*16*64*8/2; // Bpack2: 3*8*16*64*8 bf16
constexpr size_t OFF_HSB  = OFF_BP2 + (size_t)3*8*16*64*8/2;  // Hs bf16 [513*64][512]
constexpr size_t OFF_Y1P  = OFF_HSB + (size_t)513*64*512/2;   // Y1 bf16 [64][1025][256]
} // namespace

typedef __attribute__((ext_vector_type(8))) short s8v;
typedef __attribute__((ext_vector_type(4))) float f4v;

// ---- device-coherent (sc0 sc1) helpers ----
__device__ __forceinline__ void store_wt_u(unsigned* p, unsigned v) {
    asm volatile("global_store_dword %0, %1, off sc0 sc1" :: "v"(p), "v"(v) : "memory");
}
// pack h (RN bf16 hi16) + epoch tag (lo16) in ONE dword: atomic data+validity
__device__ __forceinline__ unsigned pack_pair(float h, int ep) {
    return ((__float_as_uint(h) + 0x8000u) & 0xFFFF0000u) | (unsigned)ep;
}
__device__ __forceinline__ unsigned short f2bf(float h) {
    return (unsigned short)((__float_as_uint(h) + 0x8000u) >> 16);
}
__device__ __forceinline__ float sigmoid_fast(float x) {
    return 1.f / (1.f + __expf(-x));
}
__device__ __forceinline__ float tanh_fast(float x) {   // cancellation-free
    float e = __expf(2.f * fminf(x, 15.f));
    return (e - 1.f) / (e + 1.f);
}

// W_comb^T[g][k] = W_hh[g][k] + sum_c W_dense[c][k] * W_ih[g][c]
__global__ LB void k_build_wcomb(const float* __restrict__ Wd, const float* __restrict__ Wih,
                                 const float* __restrict__ Whh, float* __restrict__ Wt) {
    int idx = blockIdx.x * 256 + threadIdx.x;
    int k = idx & (LAT - 1);
    int g = idx >> 9;
    float acc = Whh[(size_t)g * LAT + k];
#pragma unroll 4
    for (int c = 0; c < FE; ++c)
        acc = fmaf(Wd[(size_t)c * LAT + k], Wih[(size_t)g * FE + c], acc);
    Wt[(size_t)g * LAT + k] = acc;
}

// b_comb[g] = b_ih[g] + b_hh[g] + sum_c W_ih[g][c]*b_dense[c]
__global__ LB void k_build_bcomb(const float* __restrict__ Wih, const float* __restrict__ bih,
                                 const float* __restrict__ bhh, const float* __restrict__ bd,
                                 float* __restrict__ bc) {
    int g = blockIdx.x * 256 + threadIdx.x;
    float acc = bih[g] + bhh[g];
#pragma unroll 4
    for (int c = 0; c < FE; ++c) acc = fmaf(Wih[(size_t)g * FE + c], bd[c], acc);
    bc[g] = acc;
}

// A[tap][k][co] = sum_c Wd[c][k] * w1[c][co][tap]   (dense fused into deconv1)
__global__ LB void k_build_A(const float* __restrict__ Wd, const float* __restrict__ w1,
                             float* __restrict__ A) {
    int idx = blockIdx.x * 256 + threadIdx.x;      // 3*512*256
    int co = idx & 255, ki = (idx >> 8) & 511, tap = idx >> 17;
    float acc = 0.f;
#pragma unroll 4
    for (int c = 0; c < FE; ++c)
        acc = fmaf(Wd[(size_t)c * LAT + ki], w1[((size_t)c * FE + co) * 3 + tap], acc);
    A[((size_t)tap * LAT + ki) * FE + co] = acc;
}

// cbv[tap][co] = sum_c bd[c] * w1[c][co][tap]
__global__ LB void k_build_cb(const float* __restrict__ bd, const float* __restrict__ w1,
                              float* __restrict__ cbv) {
    int tap = blockIdx.x, co = threadIdx.x;
    float acc = 0.f;
#pragma unroll 4
    for (int c = 0; c < FE; ++c) acc = fmaf(bd[c], w1[((size_t)c * FE + co) * 3 + tap], acc);
    cbv[tap * FE + co] = acc;
}

// Bpack1: fragment-major bf16 layout of A for 16x16x32 MFMA B-operand.
// dst[tap][ks(16)][ct(16)][lane(64)][j(8)] = A[tap][ks*32+(lane>>4)*8+j][ct*16+(lane&15)]
__global__ LB void k_bpack1(const float* __restrict__ A, unsigned short* __restrict__ Bp1) {
    int idx = blockIdx.x * 256 + threadIdx.x;      // 393216
    int j = idx & 7, lane = (idx >> 3) & 63, ct = (idx >> 9) & 15;
    int ks = (idx >> 13) & 15, tap = idx >> 17;
    int k = ks * 32 + (lane >> 4) * 8 + j;
    int co = ct * 16 + (lane & 15);
    Bp1[idx] = f2bf(A[((size_t)tap * LAT + k) * FE + co]);
}

// zero tag buffers + BN accumulators (replay determinism)
__global__ LB void k_init_misc(float* __restrict__ gsum, float* __restrict__ gsq,
                               unsigned* __restrict__ Hx0, unsigned* __restrict__ Hx1) {
    int idx = blockIdx.x * 256 + threadIdx.x;      // 32768
    Hx0[idx] = 0u;
    Hx1[idx] = 0u;
    if (idx < FE) { gsum[idx] = 0.f; gsq[idx] = 0.f; }
}

// zero pad rows: Hs_bf t=512 (64x512) and Y1p row 1024 per batch (64x256)
__global__ LB void k_init_pads(unsigned short* __restrict__ Hsb,
                               unsigned short* __restrict__ Y1p) {
    int idx = blockIdx.x * 256 + threadIdx.x;      // 49152
    if (idx < 32768) {
        Hsb[(size_t)512 * BB * LAT + idx] = 0;
    } else {
        int j = idx - 32768;
        int b = j >> 8, co = j & 255;
        Y1p[((size_t)b * Y1S + 1024) * FE + co] = 0;
    }
}

// issue 16 sc1 pair loads from base p (stride 256 B) into u[o..o+15]
#define LDP16(o, p)                                                             \
    asm volatile(                                                               \
        "global_load_dword %0,  %16, off sc0 sc1\n\t"                           \
        "global_load_dword %1,  %16, off offset:256 sc0 sc1\n\t"                \
        "global_load_dword %2,  %16, off offset:512 sc0 sc1\n\t"                \
        "global_load_dword %3,  %16, off offset:768 sc0 sc1\n\t"                \
        "global_load_dword %4,  %16, off offset:1024 sc0 sc1\n\t"               \
        "global_load_dword %5,  %16, off offset:1280 sc0 sc1\n\t"               \
        "global_load_dword %6,  %16, off offset:1536 sc0 sc1\n\t"               \
        "global_load_dword %7,  %16, off offset:1792 sc0 sc1\n\t"               \
        "global_load_dword %8,  %16, off offset:2048 sc0 sc1\n\t"               \
        "global_load_dword %9,  %16, off offset:2304 sc0 sc1\n\t"               \
        "global_load_dword %10, %16, off offset:2560 sc0 sc1\n\t"               \
        "global_load_dword %11, %16, off offset:2816 sc0 sc1\n\t"               \
        "global_load_dword %12, %16, off offset:3072 sc0 sc1\n\t"               \
        "global_load_dword %13, %16, off offset:3328 sc0 sc1\n\t"               \
        "global_load_dword %14, %16, off offset:3584 sc0 sc1\n\t"               \
        "global_load_dword %15, %16, off offset:3840 sc0 sc1"                   \
        : "=&v"(u[(o) + 0]), "=&v"(u[(o) + 1]), "=&v"(u[(o) + 2]),              \
          "=&v"(u[(o) + 3]), "=&v"(u[(o) + 4]), "=&v"(u[(o) + 5]),              \
          "=&v"(u[(o) + 6]), "=&v"(u[(o) + 7]), "=&v"(u[(o) + 8]),              \
          "=&v"(u[(o) + 9]), "=&v"(u[(o) + 10]), "=&v"(u[(o) + 11]),            \
          "=&v"(u[(o) + 12]), "=&v"(u[(o) + 13]), "=&v"(u[(o) + 14]),           \
          "=&v"(u[(o) + 15])                                                    \
        : "v"(p))

// Persistent LSTM scan: EXACT R7 protocol (monolithic optimistic tagged load,
// single s_red, trailing __syncthreads — the sync delays next-step loads just
// enough to make first-attempt tag hits likely; removing it cost +12% in R12).
// Emits bf16 Hs for the MFMA tail.
__global__ __launch_bounds__(512, 1) void k_lstm_persist11(
    const float* __restrict__ Wt, const float* __restrict__ bc,
    const float* __restrict__ h0, const float* __restrict__ c0,
    unsigned* __restrict__ Hx0, unsigned* __restrict__ Hx1,
    unsigned short* __restrict__ Hsb)
{
    __shared__ float w_lds[8][LAT];      // 16 KB persistent
    __shared__ float s_red[8][8][BB];    // 16 KB partials
    const int w = blockIdx.x, tid = threadIdx.x;
    const int b = tid & 63, kq = tid >> 6;

    for (int i = tid; i < 1024; i += 512) {
        int c = i >> 7, k4 = i & 127;
        int g = (c >> 1) * LAT + 2 * w + (c & 1);
        ((float4*)&w_lds[c][0])[k4] = ((const float4*)&Wt[(size_t)g * LAT])[k4];
    }
    __syncthreads();

    float creg = 0.f, bs0 = 0.f, bs1 = 0.f, bs2 = 0.f, bs3 = 0.f;
    if (kq < 2) {
        int j = 2 * w + kq;
        creg = c0[(size_t)b * LAT + j];
        store_wt_u(&Hx0[j * BB + b], pack_pair(h0[(size_t)b * LAT + j], 1));
        bs0 = bc[0 * LAT + j];
        bs1 = bc[1 * LAT + j];
        bs2 = bc[2 * LAT + j];
        bs3 = bc[3 * LAT + j];
    }

    const int kbase = kq * 64;
    for (int t = 0; t < TT; ++t) {
        const unsigned* __restrict__ cur = (t & 1) ? Hx1 : Hx0;
        unsigned* __restrict__ nxt = (t & 1) ? Hx0 : Hx1;
        const int ep = t + 1;

        // monolithic optimistic load + validate (R7-proven)
        unsigned u[64];
        const unsigned* pbase = cur + (size_t)kbase * BB + b;
        int mn;
        for (;;) {
            LDP16(0, pbase);
            LDP16(16, pbase + 16 * BB);
            LDP16(32, pbase + 32 * BB);
            LDP16(48, pbase + 48 * BB);
            asm volatile("s_waitcnt vmcnt(0)" ::: "memory");
            __builtin_amdgcn_sched_barrier(0);
            mn = 0x7fffffff;
#pragma unroll
            for (int i = 0; i < 64; ++i) mn = min(mn, (int)(u[i] & 0xFFFFu));
            if (mn >= ep) break;
            __builtin_amdgcn_s_sleep(2);
        }

        float acc[8] = {0.f, 0.f, 0.f, 0.f, 0.f, 0.f, 0.f, 0.f};
#pragma unroll
        for (int i4 = 0; i4 < 16; ++i4) {
            int k = kbase + i4 * 4;
            float h0v = __uint_as_float(u[i4 * 4 + 0]);
            float h1v = __uint_as_float(u[i4 * 4 + 1]);
            float h2v = __uint_as_float(u[i4 * 4 + 2]);
            float h3v = __uint_as_float(u[i4 * 4 + 3]);
#pragma unroll
            for (int c = 0; c < 8; ++c) {
                float4 wv = *(const float4*)&w_lds[c][k];
                acc[c] = fmaf(h3v, wv.w, fmaf(h2v, wv.z,
                         fmaf(h1v, wv.y, fmaf(h0v, wv.x, acc[c]))));
            }
        }
#pragma unroll
        for (int c = 0; c < 8; ++c) s_red[kq][c][b] = acc[c];
        __syncthreads();

        if (kq < 2) {                    // waves 0-1: gates, update, publish
            int j = 2 * w + kq;
            float gv[4];
#pragma unroll
            for (int s = 0; s < 4; ++s) {
                int c = s * 2 + kq;
                float sum = (s == 0) ? bs0 : (s == 1) ? bs1 : (s == 2) ? bs2 : bs3;
#pragma unroll
                for (int q = 0; q < 8; ++q) sum += s_red[q][c][b];
                gv[s] = sum;
            }
            float ii = sigmoid_fast(gv[0]);
            float ff = sigmoid_fast(gv[1]);
            float tg = tanh_fast(gv[2]);
            float oo = sigmoid_fast(gv[3]);
            creg = ff * creg + ii * tg;
            float hv = oo * tanh_fast(creg);
            unsigned pk = pack_pair(hv, t + 2);
            store_wt_u(&nxt[j * BB + b], pk);                     // publish h^{t+1}
            Hsb[((size_t)t * BB + b) * LAT + j] = (unsigned short)(pk >> 16);
        }
        __syncthreads();                 // R7-proven: delays next loads -> tag hits
    }
}

// MFMA deconv1: even/odd outputs as 3 GEMMs (taps 1,2,0; tap0 uses rows+64,
// boundary handled by zero pad rows + bias correction). relu + BN stats + bf16 Y1.
__global__ LB void k_mfma_dc1(const unsigned short* __restrict__ Hsb,
                              const unsigned short* __restrict__ Bp1,
                              const float* __restrict__ cbv, const float* __restrict__ b1,
                              unsigned short* __restrict__ Y1p,
                              float* __restrict__ gsum, float* __restrict__ gsq) {
    __shared__ float s_sum[64], s_sq[64];
    int blk = blockIdx.x;                // 2048: bm(512) x bn(4)
    int bm = blk >> 2, bn = blk & 3;
    int tid = threadIdx.x, wv = tid >> 6, lane = tid & 63;
    if (tid < 64) { s_sum[tid] = 0.f; s_sq[tid] = 0.f; }
    __syncthreads();
    int m0 = bm * 64 + wv * 16;
    const unsigned short* pa = Hsb + (size_t)(m0 + (lane & 15)) * LAT + (lane >> 4) * 8;
    const unsigned short* pas = pa + (size_t)64 * LAT;   // rows r+64 (i+1)
    f4v acce[4], acco[4];
#pragma unroll
    for (int c = 0; c < 4; ++c) { acce[c] = (f4v){0.f,0.f,0.f,0.f}; acco[c] = (f4v){0.f,0.f,0.f,0.f}; }
    for (int ks = 0; ks < 16; ++ks) {
        s8v av = *(const s8v*)(pa + ks * 32);
        s8v as = *(const s8v*)(pas + ks * 32);
#pragma unroll
        for (int c = 0; c < 4; ++c) {
            int ct = bn * 4 + c;
            const size_t fb = ((size_t)ks * 16 + ct) * 64 + lane;
            s8v bf1 = *(const s8v*)(Bp1 + (((size_t)1 * 16 * 16 * 64) + fb) * 8);
            s8v bf2 = *(const s8v*)(Bp1 + (((size_t)2 * 16 * 16 * 64) + fb) * 8);
            s8v bf0 = *(const s8v*)(Bp1 + (fb) * 8);
            acce[c] = __builtin_amdgcn_mfma_f32_16x16x32_bf16(av, bf1, acce[c], 0, 0, 0);
            acco[c] = __builtin_amdgcn_mfma_f32_16x16x32_bf16(av, bf2, acco[c], 0, 0, 0);
            acco[c] = __builtin_amdgcn_mfma_f32_16x16x32_bf16(as, bf0, acco[c], 0, 0, 0);
        }
    }
#pragma unroll
    for (int c = 0; c < 4; ++c) {
        int col = bn * 64 + c * 16 + (lane & 15);
        float be = cbv[FE + col] + b1[col];
        float bo = cbv[2 * FE + col] + b1[col] + cbv[col];
        float c0v = cbv[col];
        float ps = 0.f, pq = 0.f;
#pragma unroll
        for (int q = 0; q < 4; ++q) {
            int r = m0 + (lane >> 4) * 4 + q;      // C/D: row=(lane>>4)*4+q, col=lane&15
            int i = r >> 6, b = r & 63;
            float ve = acce[c][q] + be;
            float vo = acco[c][q] + bo;
            if (i == TT - 1) vo -= c0v;            // tap0 invalid at i+1==512
            ve = fmaxf(ve, 0.f);
            vo = fmaxf(vo, 0.f);
            size_t base = ((size_t)b * Y1S + 2 * i) * FE + col;
            Y1p[base] = f2bf(ve);
            Y1p[base + FE] = f2bf(vo);
            ps += ve + vo;
            pq += ve * ve + vo * vo;
        }
        atomicAdd(&s_sum[c * 16 + (lane & 15)], ps);
        atomicAdd(&s_sq[c * 16 + (lane & 15)], pq);
    }
    __syncthreads();
    if (tid < 64) {
        atomicAdd(&gsum[bn * 64 + tid], s_sum[tid]);
        atomicAdd(&gsq[bn * 64 + tid], s_sq[tid]);
    }
}

__global__ LB void k_bnfin(const float* __restrict__ gsum, const float* __restrict__ gsq,
                           const float* __restrict__ gamma, const float* __restrict__ beta,
                           float* __restrict__ bnsc, float* __restrict__ bnsh) {
    int co = threadIdx.x;
    float n = (float)(BB * LO1);
    float m = gsum[co] / n;
    float v = gsq[co] / n - m * m;
    float sc = gamma[co] / sqrtf(v + EPSV);
    bnsc[co] = sc;
    bnsh[co] = beta[co] - m * sc;
}

// bias_sh[tap][co] = sum_ci bnsh[ci] * w2[ci][co][tap]
__global__ LB void k_fold_bias2(const float* __restrict__ bnsh, const float* __restrict__ w2,
                                float* __restrict__ bsh) {
    int tap = blockIdx.x, co = threadIdx.x;
    float acc = 0.f;
#pragma unroll 4
    for (int c = 0; c < FE; ++c) acc = fmaf(bnsh[c], w2[((size_t)c * FE + co) * 3 + tap], acc);
    bsh[tap * FE + co] = acc;
}

// Bpack2: fragment-major bf16 of (bnsc-folded) w2: [tap][ks(8)][ct(16)][lane][8]
__global__ LB void k_bpack2(const float* __restrict__ bnsc, const float* __restrict__ w2,
                            unsigned short* __restrict__ Bp2) {
    int idx = blockIdx.x * 256 + threadIdx.x;      // 196608
    int j = idx & 7, lane = (idx >> 3) & 63, ct = (idx >> 9) & 15;
    int ks = (idx >> 13) & 7, tap = idx >> 16;
    int ci = ks * 32 + (lane >> 4) * 8 + j;
    int co = ct * 16 + (lane & 15);
    Bp2[idx] = f2bf(bnsc[ci] * w2[((size_t)ci * FE + co) * 3 + tap]);
}

// MFMA deconv2: BN folded into weights; reads bf16 Y1 (pad row 1024 = 0),
// writes fp32 output [B][4T][F].
__global__ LB void k_mfma_dc2(const unsigned short* __restrict__ Y1p,
                              const unsigned short* __restrict__ Bp2,
                              const float* __restrict__ b2, const float* __restrict__ bsh,
                              float* __restrict__ out) {
    int blk = blockIdx.x;                // 4096: b(64) x lt(16) x bn(4)
    int b = blk >> 6, lt = (blk >> 2) & 15, bn = blk & 3;
    int tid = threadIdx.x, wv = tid >> 6, lane = tid & 63;
    int l0 = lt * 64 + wv * 16;
    const unsigned short* pa = Y1p + ((size_t)b * Y1S + l0 + (lane & 15)) * FE + (lane >> 4) * 8;
    const unsigned short* pas = pa + FE;           // rows l+1 (pad at 1024)
    f4v acce[4], acco[4];
#pragma unroll
    for (int c = 0; c < 4; ++c) { acce[c] = (f4v){0.f,0.f,0.f,0.f}; acco[c] = (f4v){0.f,0.f,0.f,0.f}; }
    for (int ks = 0; ks < 8; ++ks) {
        s8v av = *(const s8v*)(pa + ks * 32);
        s8v as = *(const s8v*)(pas + ks * 32);
#pragma unroll
        for (int c = 0; c < 4; ++c) {
            int ct = bn * 4 + c;
            const size_t fb = ((size_t)ks * 16 + ct) * 64 + lane;
            s8v bf1 = *(const s8v*)(Bp2 + (((size_t)1 * 8 * 16 * 64) + fb) * 8);
            s8v bf2 = *(const s8v*)(Bp2 + (((size_t)2 * 8 * 16 * 64) + fb) * 8);
            s8v bf0 = *(const s8v*)(Bp2 + (fb) * 8);
            acce[c] = __builtin_amdgcn_mfma_f32_16x16x32_bf16(av, bf1, acce[c], 0, 0, 0);
            acco[c] = __builtin_amdgcn_mfma_f32_16x16x32_bf16(av, bf2, acco[c], 0, 0, 0);
            acco[c] = __builtin_amdgcn_mfma_f32_16x16x32_bf16(as, bf0, acco[c], 0, 0, 0);
        }
    }
#pragma unroll
    for (int c = 0; c < 4; ++c) {
        int col = bn * 64 + c * 16 + (lane & 15);
        float be = b2[col] + bsh[FE + col];
        float bo = b2[col] + bsh[2 * FE + col] + bsh[col];
        float s0 = bsh[col];
#pragma unroll
        for (int q = 0; q < 4; ++q) {
            int l = l0 + (lane >> 4) * 4 + q;
            float ve = acce[c][q] + be;
            float vo = acco[c][q] + bo;
            if (l == LO1 - 1) vo -= s0;            // tap0 invalid at l+1==1024
            size_t base = ((size_t)b * LO2 + 2 * l) * FE + col;
            out[base] = ve;
            out[base + FE] = vo;
        }
    }
}

extern "C" void kernel_launch(void* const* d_in, const int* in_sizes, int n_in,
                              void* d_out, int out_size, void* d_ws, size_t ws_size,
                              hipStream_t stream) {
    const float* h0    = (const float*)d_in[0];
    const float* c0    = (const float*)d_in[1];
    // d_in[2] = seq_len (int, statically 512)
    const float* Wih   = (const float*)d_in[3];
    const float* bih   = (const float*)d_in[4];
    const float* Whh   = (const float*)d_in[5];
    const float* bhh   = (const float*)d_in[6];
    const float* Wd    = (const float*)d_in[7];
    const float* bd    = (const float*)d_in[8];
    const float* w1    = (const float*)d_in[9];
    const float* b1    = (const float*)d_in[10];
    const float* w2    = (const float*)d_in[11];
    const float* b2    = (const float*)d_in[12];
    const float* gamma = (const float*)d_in[13];
    const float* beta  = (const float*)d_in[14];

    float* ws   = (float*)d_ws;
    float* Wt   = ws + OFF_WT;
    float* bc   = ws + OFF_BC;
    unsigned* Hx0 = (unsigned*)(ws + OFF_HX0);
    unsigned* Hx1 = (unsigned*)(ws + OFF_HX1);
    float* A    = ws + OFF_A;
    float* cbv  = ws + OFF_CBV;
    float* gsum = ws + OFF_GSUM;
    float* gsq  = ws + OFF_GSQ;
    float* bnsc = ws + OFF_BNSC;
    float* bnsh = ws + OFF_BNSH;
    float* bsh  = ws + OFF_BSH;
    unsigned short* Bp1 = (unsigned short*)(ws + OFF_BP1);
    unsigned short* Bp2 = (unsigned short*)(ws + OFF_BP2);
    unsigned short* Hsb = (unsigned short*)(ws + OFF_HSB);
    unsigned short* Y1p = (unsigned short*)(ws + OFF_Y1P);
    float* out  = (float*)d_out;

    k_build_wcomb<<<4096, 256, 0, stream>>>(Wd, Wih, Whh, Wt);
    k_build_bcomb<<<8, 256, 0, stream>>>(Wih, bih, bhh, bd, bc);
    k_build_A<<<1536, 256, 0, stream>>>(Wd, w1, A);
    k_build_cb<<<3, 256, 0, stream>>>(bd, w1, cbv);
    k_bpack1<<<1536, 256, 0, stream>>>(A, Bp1);
    k_init_misc<<<128, 256, 0, stream>>>(gsum, gsq, Hx0, Hx1);
    k_init_pads<<<192, 256, 0, stream>>>(Hsb, Y1p);

    {
        const float* a0 = Wt;  const float* a1 = bc;
        const float* a2 = h0;  const float* a3 = c0;
        unsigned* a4 = Hx0; unsigned* a5 = Hx1; unsigned short* a6 = Hsb;
        void* args[] = { (void*)&a0, (void*)&a1, (void*)&a2, (void*)&a3,
                         (void*)&a4, (void*)&a5, (void*)&a6 };
        hipLaunchCooperativeKernel((const void*)k_lstm_persist11, dim3(NWG), dim3(512),
                                   args, 0, stream);
    }

    k_mfma_dc1<<<2048, 256, 0, stream>>>(Hsb, Bp1, cbv, b1, Y1p, gsum, gsq);
    k_bnfin<<<1, 256, 0, stream>>>(gsum, gsq, gamma, beta, bnsc, bnsh);
    k_fold_bias2<<<3, 256, 0, stream>>>(bnsh, w2, bsh);
    k_bpack2<<<768, 256, 0, stream>>>(bnsc, w2, Bp2);
    k_mfma_dc2<<<4096, 256, 0, stream>>>(Y1p, Bp2, b2, bsh, out);
}